// Round 24
// baseline (116.762 us; speedup 1.0000x reference)
//
#include <hip/hip_runtime.h>
#include <cstdint>

#define B_SZ   16384
#define H_SZ   512
#define DIN    256
#define TEMB   16
#define KP     1344            // packed K: x[0,256) h[256,768) c[768,1280) delt[1280,1296) pad
#define KPB    1344            // bytes per row (i8)
#define BH     8388608L        // B_SZ*H_SZ
#define SLOT   53248           // slot: A 2x16 KB (ks sub-tiles) + 5 W regions x 4 KB
#define GSTR   688128          // 512*KPB: gate stride in Wp8 bytes

typedef __attribute__((ext_vector_type(4))) float f32x4;
typedef __attribute__((ext_vector_type(4))) int   i32x4;

typedef const __attribute__((address_space(1))) unsigned int gu32_t;
typedef __attribute__((address_space(3)))       unsigned int lu32_t;

// gate -> W region (t and tt share region 4: never co-active)
__device__ constexpr int RG[6] = {0, 1, 4, 3, 2, 4};

__device__ __forceinline__ void gld16(const void* g, void* l) {
  __builtin_amdgcn_global_load_lds((gu32_t*)(uintptr_t)g,
                                   (lu32_t*)(unsigned int)(uintptr_t)l, 16, 0, 0);
}

__device__ __forceinline__ float sigm(float v)  { return 1.0f / (1.0f + __expf(-v)); }
__device__ __forceinline__ float tanhx(float v) { return 2.0f / (1.0f + __expf(-2.0f * v)) - 1.0f; }

__device__ __forceinline__ signed char q8(float v, float inv) {
  int q = __float2int_rn(v * inv);
  q = (q > 127) ? 127 : (q < -127 ? -127 : q);
  return (signed char)q;
}

// ---------------- fused prep (all wave-per-row, no LDS/barriers; r23-proven) ----------------
__global__ void prep_kernel(const float* __restrict__ x, const float* __restrict__ h,
                            const float* __restrict__ c, const float* __restrict__ dl,
                            const float* __restrict__ Wix, const float* __restrict__ Wih, const float* __restrict__ Wic,
                            const float* __restrict__ Wfx, const float* __restrict__ Wfh, const float* __restrict__ Wfc,
                            const float* __restrict__ Wtx, const float* __restrict__ Wtt,
                            const float* __restrict__ Wcx, const float* __restrict__ Wch,
                            const float* __restrict__ Wox, const float* __restrict__ Woh,
                            const float* __restrict__ Woc, const float* __restrict__ Wot,
                            signed char* __restrict__ Ap, float* __restrict__ sa,
                            signed char* __restrict__ Wp, float* __restrict__ sw) {
  const int tid  = threadIdx.x;
  const int lane = tid & 63;
  float4 v[6];
  float lmax = 0.f;

  if (blockIdx.x < 4096) {
    const int m = blockIdx.x * 4 + (tid >> 6);
#pragma unroll
    for (int i = 0; i < 6; ++i) {
      const int k4 = (i * 64 + lane) * 4;
      float4 t = make_float4(0.f, 0.f, 0.f, 0.f);
      if (k4 < 256)       t = *(const float4*)(x  + (size_t)m * DIN  + k4);
      else if (k4 < 768)  t = *(const float4*)(h  + (size_t)m * H_SZ + (k4 - 256));
      else if (k4 < 1280) t = *(const float4*)(c  + (size_t)m * H_SZ + (k4 - 768));
      else if (k4 < 1296) t = *(const float4*)(dl + (size_t)m * TEMB + (k4 - 1280));
      v[i] = t;
      lmax = fmaxf(lmax, fmaxf(fmaxf(fabsf(t.x), fabsf(t.y)), fmaxf(fabsf(t.z), fabsf(t.w))));
    }
#pragma unroll
    for (int s = 1; s < 64; s <<= 1)
      lmax = fmaxf(lmax, __shfl_xor(lmax, s));
    const float smax = fmaxf(lmax, 1e-20f);
    const float inv  = 127.0f / smax;
    if (lane == 0) sa[m] = smax * (1.0f / 127.0f);
#pragma unroll
    for (int i = 0; i < 6; ++i) {
      const int k4 = (i * 64 + lane) * 4;
      if (k4 < KP) {
        char4 o;
        o.x = q8(v[i].x, inv); o.y = q8(v[i].y, inv);
        o.z = q8(v[i].z, inv); o.w = q8(v[i].w, inv);
        *(char4*)(Ap + (size_t)m * KPB + k4) = o;
      }
    }
    return;
  }

  const int R = (blockIdx.x - 4096) * 4 + (tid >> 6);   // 0..3071
  const int g = R >> 9;
  const int n = R & 511;
#pragma unroll
  for (int i = 0; i < 6; ++i) {
    const int k4 = (i * 64 + lane) * 4;
    const float* src = nullptr; long o = 0;
    if (g == 0) {
      if (k4 < 256)       { src = Wix; o = (long)n * 256 + k4; }
      else if (k4 < 768)  { src = Wih; o = (long)n * 512 + (k4 - 256); }
      else if (k4 < 1280) { src = Wic; o = (long)n * 512 + (k4 - 768); }
    } else if (g == 1) {
      if (k4 < 256)       { src = Wfx; o = (long)n * 256 + k4; }
      else if (k4 < 768)  { src = Wfh; o = (long)n * 512 + (k4 - 256); }
      else if (k4 < 1280) { src = Wfc; o = (long)n * 512 + (k4 - 768); }
    } else if (g == 2) {
      if (k4 < 256)       { src = Wtx; o = (long)n * 256 + k4; }
    } else if (g == 3) {
      if (k4 < 256)       { src = Wcx; o = (long)n * 256 + k4; }
      else if (k4 < 768)  { src = Wch; o = (long)n * 512 + (k4 - 256); }
    } else if (g == 4) {
      if (k4 < 256)       { src = Wox; o = (long)n * 256 + k4; }
      else if (k4 < 768)  { src = Woh; o = (long)n * 512 + (k4 - 256); }
      else if (k4 < 1280) { src = Woc; o = (long)n * 512 + (k4 - 768); }
      else if (k4 < 1296) { src = Wot; o = (long)n * 16 + (k4 - 1280); }
    } else {
      if (k4 >= 1280 && k4 < 1296) { src = Wtt; o = (long)n * 16 + (k4 - 1280); }
    }
    float4 t = make_float4(0.f, 0.f, 0.f, 0.f);
    if (src) t = *(const float4*)(src + o);
    v[i] = t;
    lmax = fmaxf(lmax, fmaxf(fmaxf(fabsf(t.x), fabsf(t.y)), fmaxf(fabsf(t.z), fabsf(t.w))));
  }
#pragma unroll
  for (int s = 1; s < 64; s <<= 1)
    lmax = fmaxf(lmax, __shfl_xor(lmax, s));
  const float smax = fmaxf(lmax, 1e-20f);
  const float inv  = 127.0f / smax;
  if (lane == 0) sw[R] = smax * (1.0f / 127.0f);
#pragma unroll
  for (int i = 0; i < 6; ++i) {
    const int k4 = (i * 64 + lane) * 4;
    if (k4 < KP) {
      char4 o;
      o.x = q8(v[i].x, inv); o.y = q8(v[i].y, inv);
      o.z = q8(v[i].z, inv); o.w = q8(v[i].w, inv);
      *(char4*)(Wp + (size_t)R * KPB + k4) = o;
    }
  }
}

// LDS layout per slot (paired half-tiles ks=0,1; byte math per sub-tile is r11/r16-verified):
//   A:  byte = ks*16384 + row*64 + ((kgrp + (lrow>>1))&3)*16,  row in [0,256)
//   W:  byte = 32768 + RG[g]*4096 + ks*2048 + col*64 + swz,    col in [0,32)
// gld16 writes 1KB chunks linearly; per-lane source granule pre-permuted (kslot).
// A: wave w -> chunks {2w,2w+1} per ks.  W (2 chunks/gate/ks): chunk (g,c) -> wave (2g+c)&7.

template<unsigned SMASK>
__device__ __forceinline__ void stage2(char* lds, int sb, int hp,
                                       const char* sAb, const char* sWb, int wid) {
#pragma unroll
  for (int ks = 0; ks < 2; ++ks) {
    const unsigned kb = (unsigned)(2 * hp + ks) * 64u;
    gld16(sAb + kb,             lds + sb + ks * 16384 + wid * 2048);
    gld16(sAb + kb + 16u * KPB, lds + sb + ks * 16384 + wid * 2048 + 1024);
  }
#pragma unroll
  for (int g = 0; g < 6; ++g) {
    if (SMASK & (1u << g)) {
#pragma unroll
      for (int c = 0; c < 2; ++c) {
        if (((2 * g + c) & 7) == wid) {   // wave-uniform scalar compare
#pragma unroll
          for (int ks = 0; ks < 2; ++ks) {
            const unsigned kb = (unsigned)(2 * hp + ks) * 64u;
            gld16(sWb + (unsigned)g * GSTR + (unsigned)c * (16u * KPB) + kb,
                  lds + sb + 32768 + RG[g] * 4096 + ks * 2048 + c * 1024);
          }
        }
      }
    }
  }
}

// last half-tile ht=20 alone, into ks=0 of slot (gates o=4 via Wot, tt=5)
__device__ __forceinline__ void stage_last(char* lds, int sb,
                                           const char* sAb, const char* sWb, int wid) {
  const unsigned kb = 20u * 64u;
  gld16(sAb + kb,             lds + sb + wid * 2048);
  gld16(sAb + kb + 16u * KPB, lds + sb + wid * 2048 + 1024);
#pragma unroll
  for (int g = 4; g < 6; ++g) {
#pragma unroll
    for (int c = 0; c < 2; ++c) {
      if (((2 * g + c) & 7) == wid)
        gld16(sWb + (unsigned)g * GSTR + (unsigned)c * (16u * KPB) + kb,
              lds + sb + 32768 + RG[g] * 4096 + c * 1024);
    }
  }
}

template<unsigned CM>
__device__ __forceinline__ void comp2(const char* lds, int sb, int aro, int wro,
                                      i32x4 acc[6][4]) {
  const char* base = lds + sb;
#pragma unroll
  for (int ks = 0; ks < 2; ++ks) {
    i32x4 a[4];
#pragma unroll
    for (int i = 0; i < 4; ++i)
      a[i] = *(const i32x4*)(base + ks * 16384 + aro + i * 1024);
    __builtin_amdgcn_s_setprio(1);
#pragma unroll
    for (int g = 0; g < 6; ++g) {
      if (CM & (1u << g)) {
        i32x4 b = *(const i32x4*)(base + 32768 + RG[g] * 4096 + ks * 2048 + wro);
#pragma unroll
        for (int i = 0; i < 4; ++i)
          acc[g][i] = __builtin_amdgcn_mfma_i32_16x16x64_i8(a[i], b, acc[g][i], 0, 0, 0);
      }
    }
    __builtin_amdgcn_s_setprio(0);
  }
}

template<unsigned CM>
__device__ __forceinline__ void comp1(const char* lds, int sb, int aro, int wro,
                                      i32x4 acc[6][4]) {
  const char* base = lds + sb;
  i32x4 a[4];
#pragma unroll
  for (int i = 0; i < 4; ++i)
    a[i] = *(const i32x4*)(base + aro + i * 1024);
#pragma unroll
  for (int g = 0; g < 6; ++g) {
    if (CM & (1u << g)) {
      i32x4 b = *(const i32x4*)(base + 32768 + RG[g] * 4096 + wro);
#pragma unroll
      for (int i = 0; i < 4; ++i)
        acc[g][i] = __builtin_amdgcn_mfma_i32_16x16x64_i8(a[i], b, acc[g][i], 0, 0, 0);
    }
  }
}

// classic double-buffer paired phase: stage2(p+1) -> comp2(p) -> syncthreads.
template<unsigned CM, unsigned SM, bool ST>
__device__ __forceinline__ void phase2(char* lds, int p, const char* sAb, const char* sWb,
                                       int wid, int aro, int wro, i32x4 acc[6][4]) {
  if (ST) stage2<SM>(lds, ((p + 1) & 1) * SLOT, p + 1, sAb, sWb, wid);
  comp2<CM>(lds, (p & 1) * SLOT, aro, wro, acc);
  __syncthreads();
}

// ---------------- main fused kernel (i8; 6 gates; 11 paired phases) ----------------
__global__ __launch_bounds__(512, 4) void lstm_main(
    const signed char* __restrict__ Ap, const signed char* __restrict__ Wp,
    const float* __restrict__ sa, const float* __restrict__ sw,
    const float* __restrict__ c_prev,
    const float* __restrict__ b_ix, const float* __restrict__ b_fx,
    const float* __restrict__ b_tx, const float* __restrict__ b_cx,
    const float* __restrict__ b_ox,
    float* __restrict__ out)
{
  __shared__ __align__(16) char lds[2 * SLOT];   // 106496 B (1 wg/CU; regs pin it anyway)

  const int tid  = threadIdx.x;
  const int lane = tid & 63;
  const int wid  = tid >> 6;

  // XCD swizzle: XCD k owns col-blocks {2k,2k+1} (W slice L2-resident)
  const int bid = blockIdx.x;
  const int xcd = bid & 7;
  const int idx = bid >> 3;                  // 0..127
  const int cb  = (xcd << 1) | (idx & 1);    // 0..15
  const int rb  = idx >> 1;                  // 0..63
  const unsigned brow = (unsigned)rb * 256u;
  const int bcol = cb * 32;

  const int wr  = (wid >> 1) * 64;           // wave rows [wr, wr+64)
  const int wcg = (wid & 1) * 16;            // wave cols [wcg, wcg+16)
  const int lrow = lane & 15;
  const int kgrp = lane >> 4;

  i32x4 acc[6][4];
  {
    i32x4 z = {0, 0, 0, 0};
#pragma unroll
    for (int g = 0; g < 6; ++g)
#pragma unroll
      for (int i = 0; i < 4; ++i) acc[g][i] = z;
  }

  // swizzled read offsets (sub-tile byte math identical to r11/r16)
  const int sread = ((kgrp + (lrow >> 1)) & 3) << 4;
  const int aro = (wr + lrow) * 64 + sread;
  const int wro = (wcg + lrow) * 64 + sread;   // region-relative

  const int l4 = lane >> 2;
  const int kslot = (((lane & 3) - ((lane >> 3) & 3)) & 3) << 4;
  const char* sAb = (const char*)Ap + (size_t)(brow + wid * 32 + l4) * KPB + kslot;
  const char* sWb = (const char*)Wp + (size_t)(bcol + l4) * KPB + kslot;

  // prologue: paired half-tiles {0,1}
  stage2<0x1F>(lds, 0, 0, sAb, sWb, wid);
  __syncthreads();

  // 11 phases: x p0-1 (0x1F) | h p2-5 (0x1B) | c p6-9 (0x13) | delt p10 (0x30)
  phase2<0x1F, 0x1F, true>(lds, 0, sAb, sWb, wid, aro, wro, acc);
  phase2<0x1F, 0x1B, true>(lds, 1, sAb, sWb, wid, aro, wro, acc);
#pragma unroll 1
  for (int p = 2; p < 5; ++p)
    phase2<0x1B, 0x1B, true>(lds, p, sAb, sWb, wid, aro, wro, acc);
  phase2<0x1B, 0x13, true>(lds, 5, sAb, sWb, wid, aro, wro, acc);
#pragma unroll 1
  for (int p = 6; p < 9; ++p)
    phase2<0x13, 0x13, true>(lds, p, sAb, sWb, wid, aro, wro, acc);
  {  // p=9: comp c-seg, stage ht20 alone into slot0
    stage_last(lds, 0, sAb, sWb, wid);
    comp2<0x13>(lds, SLOT, aro, wro, acc);
    __syncthreads();
  }
  comp1<0x30>(lds, 0, aro, wro, acc);   // p=10

  // ---------------- fused epilogue (dequant + activations) ----------------
  const int n = bcol + wcg + lrow;
  const float bi  = b_ix[n], bff = b_fx[n], bt = b_tx[n], bc = b_cx[n], bo = b_ox[n];
  const float s0 = sw[0 * 512 + n], s1 = sw[1 * 512 + n], s2 = sw[2 * 512 + n];
  const float s3 = sw[3 * 512 + n], s4 = sw[4 * 512 + n], s5 = sw[5 * 512 + n];
  const int rbase = kgrp * 4;
#pragma unroll
  for (int i = 0; i < 4; ++i) {
    const int m0 = (int)brow + wr + 16 * i + rbase;
    const float4 sa4 = *(const float4*)(sa + m0);
#pragma unroll
    for (int r = 0; r < 4; ++r) {
      const long m   = m0 + r;
      const long off = m * H_SZ + n;
      const float sr = (r == 0) ? sa4.x : (r == 1) ? sa4.y : (r == 2) ? sa4.z : sa4.w;
      const float iv = sigm((float)acc[0][i][r] * sr * s0 + bi);
      const float fv = sigm((float)acc[1][i][r] * sr * s1 + bff);
      const float Tv = sigm((float)acc[2][i][r] * sr * s2 + bt
                            + sigm((float)acc[5][i][r] * sr * s5));
      const float kv = tanhx((float)acc[3][i][r] * sr * s3 + bc);
      const float ov = sigm((float)acc[4][i][r] * sr * s4 + bo);
      const float cp = c_prev[off];
      const float cn = iv * Tv * kv + fv * cp;
      out[off]          = ov * tanhx(cn);
      out[BH + off]     = cn;
      out[2 * BH + off] = Tv;
    }
  }
}

extern "C" void kernel_launch(void* const* d_in, const int* in_sizes, int n_in,
                              void* d_out, int out_size, void* d_ws, size_t ws_size,
                              hipStream_t stream) {
  const float* x      = (const float*)d_in[0];
  const float* h      = (const float*)d_in[1];
  const float* c_prev = (const float*)d_in[2];
  const float* dl     = (const float*)d_in[3];
  const float* W_ix = (const float*)d_in[4];
  const float* b_ix = (const float*)d_in[5];
  const float* W_ih = (const float*)d_in[6];
  const float* W_ic = (const float*)d_in[7];
  const float* W_fx = (const float*)d_in[8];
  const float* b_fx = (const float*)d_in[9];
  const float* W_fh = (const float*)d_in[10];
  const float* W_fc = (const float*)d_in[11];
  const float* W_tx = (const float*)d_in[12];
  const float* b_tx = (const float*)d_in[13];
  const float* W_tt = (const float*)d_in[14];
  const float* W_cx = (const float*)d_in[15];
  const float* b_cx = (const float*)d_in[16];
  const float* W_ch = (const float*)d_in[17];
  const float* W_ox = (const float*)d_in[18];
  const float* b_ox = (const float*)d_in[19];
  const float* W_oh = (const float*)d_in[20];
  const float* W_oc = (const float*)d_in[21];
  const float* W_ot = (const float*)d_in[22];

  signed char* Ap8 = (signed char*)d_ws;                             // 22,020,096 B
  signed char* Wp8 = (signed char*)d_ws + (size_t)B_SZ * KPB;        // + 4,128,768 B
  float* sa = (float*)((char*)d_ws + (size_t)B_SZ * KPB + 6L * H_SZ * KPB);   // 64 KB
  float* sw = sa + B_SZ;                                             // 12 KB

  prep_kernel<<<4096 + 768, 256, 0, stream>>>(
      x, h, c_prev, dl,
      W_ix, W_ih, W_ic, W_fx, W_fh, W_fc, W_tx, W_tt, W_cx, W_ch,
      W_ox, W_oh, W_oc, W_ot, Ap8, sa, Wp8, sw);

  lstm_main<<<1024, 512, 0, stream>>>(Ap8, Wp8, sa, sw, c_prev,
                                      b_ix, b_fx, b_tx, b_cx, b_ox,
                                      (float*)d_out);
}

// Round 25
// 109.262 us; speedup vs baseline: 1.0686x; 1.0686x over previous
//
#include <hip/hip_runtime.h>
#include <cstdint>

#define B_SZ   16384
#define H_SZ   512
#define DIN    256
#define TEMB   16
#define KP     1344            // packed K: x[0,256) h[256,768) c[768,1280) delt[1280,1296) pad
#define KPB    1344            // bytes per row (i8)
#define BH     8388608L        // B_SZ*H_SZ
#define SLOT   26624           // LDS slot: A 16 KB (256 rows x 64 B) + 5 W regions x 2 KB
#define GSTR   688128          // 512*KPB: gate stride in Wp8 bytes

typedef __attribute__((ext_vector_type(4))) float f32x4;
typedef __attribute__((ext_vector_type(4))) int   i32x4;

typedef const __attribute__((address_space(1))) unsigned int gu32_t;
typedef __attribute__((address_space(3)))       unsigned int lu32_t;

// gate -> W region (t and tt share region 4: never co-active)
__device__ constexpr int RG[6] = {0, 1, 4, 3, 2, 4};

__device__ __forceinline__ void gld16(const void* g, void* l) {
  __builtin_amdgcn_global_load_lds((gu32_t*)(uintptr_t)g,
                                   (lu32_t*)(unsigned int)(uintptr_t)l, 16, 0, 0);
}

__device__ __forceinline__ float sigm(float v)  { return 1.0f / (1.0f + __expf(-v)); }
__device__ __forceinline__ float tanhx(float v) { return 2.0f / (1.0f + __expf(-2.0f * v)) - 1.0f; }

__device__ __forceinline__ signed char q8(float v, float inv) {
  int q = __float2int_rn(v * inv);
  q = (q > 127) ? 127 : (q < -127 ? -127 : q);
  return (signed char)q;
}

// ---------------- fused prep (all wave-per-row, no LDS/barriers) ----------------
// blocks [0,4096): A rows (4 rows/block).  blocks [4096,4864): W rows (4 rows/block).
__global__ void prep_kernel(const float* __restrict__ x, const float* __restrict__ h,
                            const float* __restrict__ c, const float* __restrict__ dl,
                            const float* __restrict__ Wix, const float* __restrict__ Wih, const float* __restrict__ Wic,
                            const float* __restrict__ Wfx, const float* __restrict__ Wfh, const float* __restrict__ Wfc,
                            const float* __restrict__ Wtx, const float* __restrict__ Wtt,
                            const float* __restrict__ Wcx, const float* __restrict__ Wch,
                            const float* __restrict__ Wox, const float* __restrict__ Woh,
                            const float* __restrict__ Woc, const float* __restrict__ Wot,
                            signed char* __restrict__ Ap, float* __restrict__ sa,
                            signed char* __restrict__ Wp, float* __restrict__ sw) {
  const int tid  = threadIdx.x;
  const int lane = tid & 63;
  float4 v[6];
  float lmax = 0.f;

  if (blockIdx.x < 4096) {
    // ---- A row m = [x|h|c|delt|0] ----
    const int m = blockIdx.x * 4 + (tid >> 6);
#pragma unroll
    for (int i = 0; i < 6; ++i) {
      const int k4 = (i * 64 + lane) * 4;
      float4 t = make_float4(0.f, 0.f, 0.f, 0.f);
      if (k4 < 256)       t = *(const float4*)(x  + (size_t)m * DIN  + k4);
      else if (k4 < 768)  t = *(const float4*)(h  + (size_t)m * H_SZ + (k4 - 256));
      else if (k4 < 1280) t = *(const float4*)(c  + (size_t)m * H_SZ + (k4 - 768));
      else if (k4 < 1296) t = *(const float4*)(dl + (size_t)m * TEMB + (k4 - 1280));
      v[i] = t;
      lmax = fmaxf(lmax, fmaxf(fmaxf(fabsf(t.x), fabsf(t.y)), fmaxf(fabsf(t.z), fabsf(t.w))));
    }
#pragma unroll
    for (int s = 1; s < 64; s <<= 1)
      lmax = fmaxf(lmax, __shfl_xor(lmax, s));
    const float smax = fmaxf(lmax, 1e-20f);
    const float inv  = 127.0f / smax;
    if (lane == 0) sa[m] = smax * (1.0f / 127.0f);
#pragma unroll
    for (int i = 0; i < 6; ++i) {
      const int k4 = (i * 64 + lane) * 4;
      if (k4 < KP) {
        char4 o;
        o.x = q8(v[i].x, inv); o.y = q8(v[i].y, inv);
        o.z = q8(v[i].z, inv); o.w = q8(v[i].w, inv);
        *(char4*)(Ap + (size_t)m * KPB + k4) = o;
      }
    }
    return;
  }

  // ---- W row R in packed-gate layout ----
  const int R = (blockIdx.x - 4096) * 4 + (tid >> 6);   // 0..3071
  const int g = R >> 9;
  const int n = R & 511;
#pragma unroll
  for (int i = 0; i < 6; ++i) {
    const int k4 = (i * 64 + lane) * 4;
    const float* src = nullptr; long o = 0;
    if (g == 0) {
      if (k4 < 256)       { src = Wix; o = (long)n * 256 + k4; }
      else if (k4 < 768)  { src = Wih; o = (long)n * 512 + (k4 - 256); }
      else if (k4 < 1280) { src = Wic; o = (long)n * 512 + (k4 - 768); }
    } else if (g == 1) {
      if (k4 < 256)       { src = Wfx; o = (long)n * 256 + k4; }
      else if (k4 < 768)  { src = Wfh; o = (long)n * 512 + (k4 - 256); }
      else if (k4 < 1280) { src = Wfc; o = (long)n * 512 + (k4 - 768); }
    } else if (g == 2) {
      if (k4 < 256)       { src = Wtx; o = (long)n * 256 + k4; }
    } else if (g == 3) {
      if (k4 < 256)       { src = Wcx; o = (long)n * 256 + k4; }
      else if (k4 < 768)  { src = Wch; o = (long)n * 512 + (k4 - 256); }
    } else if (g == 4) {
      if (k4 < 256)       { src = Wox; o = (long)n * 256 + k4; }
      else if (k4 < 768)  { src = Woh; o = (long)n * 512 + (k4 - 256); }
      else if (k4 < 1280) { src = Woc; o = (long)n * 512 + (k4 - 768); }
      else if (k4 < 1296) { src = Wot; o = (long)n * 16 + (k4 - 1280); }
    } else {
      if (k4 >= 1280 && k4 < 1296) { src = Wtt; o = (long)n * 16 + (k4 - 1280); }
    }
    float4 t = make_float4(0.f, 0.f, 0.f, 0.f);
    if (src) t = *(const float4*)(src + o);
    v[i] = t;
    lmax = fmaxf(lmax, fmaxf(fmaxf(fabsf(t.x), fabsf(t.y)), fmaxf(fabsf(t.z), fabsf(t.w))));
  }
#pragma unroll
  for (int s = 1; s < 64; s <<= 1)
    lmax = fmaxf(lmax, __shfl_xor(lmax, s));
  const float smax = fmaxf(lmax, 1e-20f);
  const float inv  = 127.0f / smax;
  if (lane == 0) sw[R] = smax * (1.0f / 127.0f);
#pragma unroll
  for (int i = 0; i < 6; ++i) {
    const int k4 = (i * 64 + lane) * 4;
    if (k4 < KP) {
      char4 o;
      o.x = q8(v[i].x, inv); o.y = q8(v[i].y, inv);
      o.z = q8(v[i].z, inv); o.w = q8(v[i].w, inv);
      *(char4*)(Wp + (size_t)R * KPB + k4) = o;
    }
  }
}

// LDS layout per slot (K-phase = 64 i8 elems = 64 B per row; r11/r16-verified byte math):
//   A: byte = row*64 + ((kgrp + (lrow>>1))&3)*16,  row in [0,256)
//   W: byte = 16384 + RG[g]*2048 + col*64 + swz,   col in [0,32)
// gld16 writes 1KB chunks linearly; per-lane source granule pre-permuted (kslot).

// gates: 0=i 1=f 2=t 3=k 4=o 5=tt.  A: wave w -> chunks {2w,2w+1}.
// W (2 chunks/gate): chunk (g,c) -> wave (2g+c)&7.
template<unsigned SMASK>
__device__ __forceinline__ void stage(char* lds, int sb, int ht,
                                      const char* sAb, const char* sWb, int wid) {
  const unsigned kb = (unsigned)ht * 64u;
  gld16(sAb + kb,              lds + sb + wid * 2048);
  gld16(sAb + kb + 16u * KPB,  lds + sb + wid * 2048 + 1024);
#pragma unroll
  for (int g = 0; g < 6; ++g) {
    if (SMASK & (1u << g)) {
#pragma unroll
      for (int c = 0; c < 2; ++c) {
        if (((2 * g + c) & 7) == wid)   // wave-uniform scalar compare
          gld16(sWb + (unsigned)g * GSTR + (unsigned)c * (16u * KPB) + kb,
                lds + sb + 16384 + RG[g] * 2048 + c * 1024);
      }
    }
  }
}

template<unsigned CM>
__device__ __forceinline__ void comp(const char* lds, int sb, int aro, int wro,
                                     i32x4 acc[6][4]) {
  const char* base = lds + sb;
  i32x4 a[4];
#pragma unroll
  for (int i = 0; i < 4; ++i)
    a[i] = *(const i32x4*)(base + aro + i * 1024);
  __builtin_amdgcn_s_setprio(1);
#pragma unroll
  for (int g = 0; g < 6; ++g) {
    if (CM & (1u << g)) {
      i32x4 b = *(const i32x4*)(base + 16384 + RG[g] * 2048 + wro);
#pragma unroll
      for (int i = 0; i < 4; ++i)
        acc[g][i] = __builtin_amdgcn_mfma_i32_16x16x64_i8(a[i], b, acc[g][i], 0, 0, 0);
    }
  }
  __builtin_amdgcn_s_setprio(0);
}

// classic double-buffer phase (r16/r22-proven): stage(h+1) -> comp(h) -> syncthreads.
template<unsigned CM, unsigned SM, bool ST>
__device__ __forceinline__ void phase(char* lds, int h, const char* sAb, const char* sWb,
                                      int wid, int aro, int wro, i32x4 acc[6][4]) {
  if (ST) stage<SM>(lds, ((h + 1) & 1) * SLOT, h + 1, sAb, sWb, wid);
  comp<CM>(lds, (h & 1) * SLOT, aro, wro, acc);
  __syncthreads();
}

// ---------------- main fused kernel (i8; 6 gates; 21 phases; r16/r22-proven) ----------------
__global__ __launch_bounds__(512, 4) void lstm_main(
    const signed char* __restrict__ Ap, const signed char* __restrict__ Wp,
    const float* __restrict__ sa, const float* __restrict__ sw,
    const float* __restrict__ c_prev,
    const float* __restrict__ b_ix, const float* __restrict__ b_fx,
    const float* __restrict__ b_tx, const float* __restrict__ b_cx,
    const float* __restrict__ b_ox,
    float* __restrict__ out)
{
  __shared__ __align__(16) char lds[2 * SLOT];   // 53248 B

  const int tid  = threadIdx.x;
  const int lane = tid & 63;
  const int wid  = tid >> 6;

  // XCD swizzle: XCD k owns col-blocks {2k,2k+1} (W slice L2-resident)
  const int bid = blockIdx.x;
  const int xcd = bid & 7;
  const int idx = bid >> 3;                  // 0..127
  const int cb  = (xcd << 1) | (idx & 1);    // 0..15
  const int rb  = idx >> 1;                  // 0..63
  const unsigned brow = (unsigned)rb * 256u;
  const int bcol = cb * 32;

  const int wr  = (wid >> 1) * 64;           // wave rows [wr, wr+64)
  const int wcg = (wid & 1) * 16;            // wave cols [wcg, wcg+16)
  const int lrow = lane & 15;
  const int kgrp = lane >> 4;

  i32x4 acc[6][4];
  {
    i32x4 z = {0, 0, 0, 0};
#pragma unroll
    for (int g = 0; g < 6; ++g)
#pragma unroll
      for (int i = 0; i < 4; ++i) acc[g][i] = z;
  }

  // swizzled read offsets (byte math identical to r11/r16)
  const int sread = ((kgrp + (lrow >> 1)) & 3) << 4;
  const int aro = (wr + lrow) * 64 + sread;
  const int wro = (wcg + lrow) * 64 + sread;   // region-relative

  const int l4 = lane >> 2;
  const int kslot = (((lane & 3) - ((lane >> 3) & 3)) & 3) << 4;
  const char* sAb = (const char*)Ap + (size_t)(brow + wid * 32 + l4) * KPB + kslot;
  const char* sWb = (const char*)Wp + (size_t)(bcol + l4) * KPB + kslot;

  // prologue
  stage<0x1F>(lds, 0, 0, sAb, sWb, wid);
  __syncthreads();

  // 21 phases: x h0-3 (0x1F) | h h4-11 (0x1B) | c h12-19 (0x13) | delt h20 (0x30)
#pragma unroll 1
  for (int h = 0; h < 3; ++h)
    phase<0x1F, 0x1F, true>(lds, h, sAb, sWb, wid, aro, wro, acc);
  phase<0x1F, 0x1B, true>(lds, 3, sAb, sWb, wid, aro, wro, acc);
#pragma unroll 1
  for (int h = 4; h < 11; ++h)
    phase<0x1B, 0x1B, true>(lds, h, sAb, sWb, wid, aro, wro, acc);
  phase<0x1B, 0x13, true>(lds, 11, sAb, sWb, wid, aro, wro, acc);
#pragma unroll 1
  for (int h = 12; h < 19; ++h)
    phase<0x13, 0x13, true>(lds, h, sAb, sWb, wid, aro, wro, acc);
  phase<0x13, 0x30, true>(lds, 19, sAb, sWb, wid, aro, wro, acc);
  comp<0x30>(lds, (20 & 1) * SLOT, aro, wro, acc);

  // ---------------- fused epilogue (dequant + activations) ----------------
  const int n = bcol + wcg + lrow;
  const float bi  = b_ix[n], bff = b_fx[n], bt = b_tx[n], bc = b_cx[n], bo = b_ox[n];
  const float s0 = sw[0 * 512 + n], s1 = sw[1 * 512 + n], s2 = sw[2 * 512 + n];
  const float s3 = sw[3 * 512 + n], s4 = sw[4 * 512 + n], s5 = sw[5 * 512 + n];
  const int rbase = kgrp * 4;
#pragma unroll
  for (int i = 0; i < 4; ++i) {
    const int m0 = (int)brow + wr + 16 * i + rbase;
    const float4 sa4 = *(const float4*)(sa + m0);
#pragma unroll
    for (int r = 0; r < 4; ++r) {
      const long m   = m0 + r;
      const long off = m * H_SZ + n;
      const float sr = (r == 0) ? sa4.x : (r == 1) ? sa4.y : (r == 2) ? sa4.z : sa4.w;
      const float iv = sigm((float)acc[0][i][r] * sr * s0 + bi);
      const float fv = sigm((float)acc[1][i][r] * sr * s1 + bff);
      const float Tv = sigm((float)acc[2][i][r] * sr * s2 + bt
                            + sigm((float)acc[5][i][r] * sr * s5));
      const float kv = tanhx((float)acc[3][i][r] * sr * s3 + bc);
      const float ov = sigm((float)acc[4][i][r] * sr * s4 + bo);
      const float cp = c_prev[off];
      const float cn = iv * Tv * kv + fv * cp;
      out[off]          = ov * tanhx(cn);
      out[BH + off]     = cn;
      out[2 * BH + off] = Tv;
    }
  }
}

extern "C" void kernel_launch(void* const* d_in, const int* in_sizes, int n_in,
                              void* d_out, int out_size, void* d_ws, size_t ws_size,
                              hipStream_t stream) {
  const float* x      = (const float*)d_in[0];
  const float* h      = (const float*)d_in[1];
  const float* c_prev = (const float*)d_in[2];
  const float* dl     = (const float*)d_in[3];
  const float* W_ix = (const float*)d_in[4];
  const float* b_ix = (const float*)d_in[5];
  const float* W_ih = (const float*)d_in[6];
  const float* W_ic = (const float*)d_in[7];
  const float* W_fx = (const float*)d_in[8];
  const float* b_fx = (const float*)d_in[9];
  const float* W_fh = (const float*)d_in[10];
  const float* W_fc = (const float*)d_in[11];
  const float* W_tx = (const float*)d_in[12];
  const float* b_tx = (const float*)d_in[13];
  const float* W_tt = (const float*)d_in[14];
  const float* W_cx = (const float*)d_in[15];
  const float* b_cx = (const float*)d_in[16];
  const float* W_ch = (const float*)d_in[17];
  const float* W_ox = (const float*)d_in[18];
  const float* b_ox = (const float*)d_in[19];
  const float* W_oh = (const float*)d_in[20];
  const float* W_oc = (const float*)d_in[21];
  const float* W_ot = (const float*)d_in[22];

  signed char* Ap8 = (signed char*)d_ws;                             // 22,020,096 B
  signed char* Wp8 = (signed char*)d_ws + (size_t)B_SZ * KPB;        // + 4,128,768 B
  float* sa = (float*)((char*)d_ws + (size_t)B_SZ * KPB + 6L * H_SZ * KPB);   // 64 KB
  float* sw = sa + B_SZ;                                             // 12 KB

  prep_kernel<<<4096 + 768, 256, 0, stream>>>(
      x, h, c_prev, dl,
      W_ix, W_ih, W_ic, W_fx, W_fh, W_fc, W_tx, W_tt, W_cx, W_ch,
      W_ox, W_oh, W_oc, W_ot, Ap8, sa, Wp8, sw);

  lstm_main<<<1024, 512, 0, stream>>>(Ap8, Wp8, sa, sw, c_prev,
                                      b_ix, b_fx, b_tx, b_cx, b_ox,
                                      (float*)d_out);
}